// Round 12
// baseline (813.630 us; speedup 1.0000x reference)
//
#include <hip/hip_runtime.h>
#include <hip/hip_cooperative_groups.h>

namespace cg = cooperative_groups;

typedef __attribute__((ext_vector_type(8))) short short8;
typedef __attribute__((ext_vector_type(4))) float f32x4;

__device__ __forceinline__ float lrelu02(float a) { return a > 0.0f ? a : 0.2f * a; }

__device__ __forceinline__ unsigned bf16rne(float f) {
    unsigned u = __float_as_uint(f);
    return (u + 0x7fffu + ((u >> 16) & 1u)) >> 16;
}

// ---------- cooperative CSR build: zero | rank | scan | scan_add | fill ----------
__global__ __launch_bounds__(256, 8) void k_csr(
    const int* __restrict__ ei, int* __restrict__ deg, int* __restrict__ rank,
    int* __restrict__ rowptr, int* __restrict__ bsum, int* __restrict__ col,
    int E, int N)
{
    cg::grid_group grid = cg::this_grid();
    const int t = threadIdx.x;
    const int tid = blockIdx.x * 256 + t;
    const int nthr = gridDim.x * 256;
    const int ET = E + N;
    const int nblk = (N + 2047) >> 11;
    __shared__ int ts[256];

    // P0: zero deg
    for (int i = tid; i < N; i += nthr) deg[i] = 0;
    grid.sync();

    // P1: rank (one returning atomic per edge)
    int E4 = E & ~3;
    for (int b = tid * 4; b < E4; b += nthr * 4) {
        int4 d = *(const int4*)(ei + E + b);
        int4 r;
        r.x = atomicAdd(&deg[d.x], 1);
        r.y = atomicAdd(&deg[d.y], 1);
        r.z = atomicAdd(&deg[d.z], 1);
        r.w = atomicAdd(&deg[d.w], 1);
        *(int4*)(rank + b) = r;
    }
    for (int e = E4 + tid; e < E; e += nthr)
        rank[e] = atomicAdd(&deg[ei[E + e]], 1);
    for (int i = tid; i < N; i += nthr)
        rank[E + i] = atomicAdd(&deg[i], 1);            // self loops
    grid.sync();

    // P2: per-block local scan (blocks < nblk; 2048 elems each)
    if (blockIdx.x < (unsigned)nblk) {
        const int base = blockIdx.x * 2048 + t * 8;
        int v[8];
        int s = 0;
        #pragma unroll
        for (int j = 0; j < 8; ++j) {
            int idx = base + j;
            v[j] = (idx < N) ? deg[idx] : 0;
            s += v[j];
        }
        ts[t] = s;
        __syncthreads();
        #pragma unroll
        for (int off = 1; off < 256; off <<= 1) {
            int u = (t >= off) ? ts[t - off] : 0;
            __syncthreads();
            ts[t] += u;
            __syncthreads();
        }
        int ex = (t == 0) ? 0 : ts[t - 1];
        #pragma unroll
        for (int j = 0; j < 8; ++j) {
            int idx = base + j;
            if (idx < N) rowptr[idx] = ex;
            ex += v[j];
        }
        if (t == 255) bsum[blockIdx.x] = ts[255];
    }
    grid.sync();

    // P3: add block offsets (per-block bsum prefix via wave reduce)
    if (blockIdx.x < (unsigned)nblk) {
        __shared__ int soff;
        if (t < 64) {
            int v = (t < (int)blockIdx.x) ? bsum[t] : 0;    // nblk <= 64
            #pragma unroll
            for (int m = 32; m >= 1; m >>= 1) v += __shfl_xor(v, m);
            if (t == 0) soff = v;
        }
        __syncthreads();
        int off = soff;
        const int base = blockIdx.x * 2048 + t * 8;
        #pragma unroll
        for (int j = 0; j < 8; ++j) {
            int idx = base + j;
            if (idx < N) rowptr[idx] += off;
        }
        if (blockIdx.x == 0 && t == 0) rowptr[N] = ET;
    }
    grid.sync();

    // P4: fill (atomic-free)
    for (int b = tid * 4; b < E4; b += nthr * 4) {
        int4 d = *(const int4*)(ei + E + b);
        int4 s = *(const int4*)(ei + b);
        int4 r = *(const int4*)(rank + b);
        col[rowptr[d.x] + r.x] = s.x;
        col[rowptr[d.y] + r.y] = s.y;
        col[rowptr[d.z] + r.z] = s.z;
        col[rowptr[d.w] + r.w] = s.w;
    }
    for (int e = E4 + tid; e < E; e += nthr)
        col[rowptr[ei[E + e]] + rank[e]] = ei[e];
    for (int i = tid; i < N; i += nthr)
        col[rowptr[i] + rank[E + i]] = i;
}

// -------------------- GEMM1 (MFMA bf16) --------------------
__global__ __launch_bounds__(256) void k_gemm1(
    const float* __restrict__ x, const float* __restrict__ W,
    const float* __restrict__ attS, const float* __restrict__ attD,
    unsigned short* __restrict__ h1, float* __restrict__ as1, float* __restrict__ ad1, int N)
{
    __shared__ unsigned short Wt[128 * 128];
    __shared__ unsigned short xs[64 * 128];

    const int t = threadIdx.x;
    const int lane = t & 63;
    const int wv = t >> 6;
    const int ln = lane & 15;
    const int lg = lane >> 4;
    const int r0 = blockIdx.x * 64;

    #pragma unroll
    for (int i = 0; i < 16; ++i) {
        int flat = i * 256 + t;
        int n = flat & 127;
        int k0 = (flat >> 7) * 4;
        float v0 = W[(size_t)(k0 + 0) * 128 + n];
        float v1 = W[(size_t)(k0 + 1) * 128 + n];
        float v2 = W[(size_t)(k0 + 2) * 128 + n];
        float v3 = W[(size_t)(k0 + 3) * 128 + n];
        uint2 pk;
        pk.x = bf16rne(v0) | (bf16rne(v1) << 16);
        pk.y = bf16rne(v2) | (bf16rne(v3) << 16);
        int byteo = n * 256 + ((k0 * 2) ^ ((n & 7) << 4));
        *(uint2*)((char*)Wt + byteo) = pk;
    }
    {
        int mbase = t >> 5, k0 = (t & 31) * 4;
        #pragma unroll
        for (int it = 0; it < 8; ++it) {
            int m = mbase + it * 8;
            int rr = r0 + m;
            float4 v = make_float4(0.f, 0.f, 0.f, 0.f);
            if (rr < N) v = *(const float4*)&x[(size_t)rr * 128 + k0];
            unsigned lo = bf16rne(v.x) | (bf16rne(v.y) << 16);
            unsigned hi = bf16rne(v.z) | (bf16rne(v.w) << 16);
            int byteo = m * 256 + ((k0 * 2) ^ ((m & 7) << 4));
            *(uint2*)((char*)xs + byteo) = make_uint2(lo, hi);
        }
    }
    __syncthreads();

    f32x4 acc[8];
    #pragma unroll
    for (int i = 0; i < 8; ++i) acc[i] = (f32x4)(0.f);

    #pragma unroll
    for (int kk = 0; kk < 4; ++kk) {
        int kb = (kk * 32 + lg * 8) * 2;
        int am = wv * 16 + ln;
        short8 a = *(const short8*)((char*)xs + am * 256 + (kb ^ ((am & 7) << 4)));
        #pragma unroll
        for (int tile = 0; tile < 8; ++tile) {
            int n = tile * 16 + ln;
            short8 b = *(const short8*)((char*)Wt + n * 256 + (kb ^ ((n & 7) << 4)));
            acc[tile] = __builtin_amdgcn_mfma_f32_16x16x32_bf16(a, b, acc[tile], 0, 0, 0);
        }
    }

    float aSt[8], aDt[8];
    #pragma unroll
    for (int tile = 0; tile < 8; ++tile) {
        aSt[tile] = attS[tile * 16 + ln];
        aDt[tile] = attD[tile * 16 + ln];
    }
    #pragma unroll
    for (int r = 0; r < 4; ++r) {
        int row = r0 + wv * 16 + lg * 4 + r;
        #pragma unroll
        for (int h = 0; h < 4; ++h) {
            float s = acc[2*h][r] * aSt[2*h] + acc[2*h+1][r] * aSt[2*h+1];
            float d = acc[2*h][r] * aDt[2*h] + acc[2*h+1][r] * aDt[2*h+1];
            s += __shfl_xor(s, 1); s += __shfl_xor(s, 2); s += __shfl_xor(s, 4); s += __shfl_xor(s, 8);
            d += __shfl_xor(d, 1); d += __shfl_xor(d, 2); d += __shfl_xor(d, 4); d += __shfl_xor(d, 8);
            if (ln == h * 4 + r && row < N) {
                as1[row * 4 + h] = s;
                ad1[row * 4 + h] = d;
            }
        }
    }

    __syncthreads();
    #pragma unroll
    for (int tile = 0; tile < 8; ++tile) {
        #pragma unroll
        for (int r = 0; r < 4; ++r) {
            int m = wv * 16 + lg * 4 + r;
            int byteo = m * 256 + (((tile * 16 + ln) * 2) ^ ((m & 7) << 4));
            *(unsigned short*)((char*)xs + byteo) = (unsigned short)bf16rne(acc[tile][r]);
        }
    }
    __syncthreads();
    #pragma unroll
    for (int it = 0; it < 4; ++it) {
        int idx = t + it * 256;
        int m = idx >> 4, o = idx & 15;
        int byteo = m * 256 + ((o * 16) ^ ((m & 7) << 4));
        if (r0 + m < N)
            *(uint4*)((char*)(h1 + (size_t)(r0 + m) * 128) + o * 16) =
                *(const uint4*)((const char*)xs + byteo);
    }
}

// ---------- layer-1 fused softmax+aggregate ----------
__global__ __launch_bounds__(256) void k_agg1(
    const unsigned short* __restrict__ h1, const float* __restrict__ as1,
    const float* __restrict__ ad1, const int* __restrict__ rowptr,
    const int* __restrict__ col, const float* __restrict__ b1,
    unsigned short* __restrict__ out1, int N)
{
    int wid = (int)(((unsigned)blockIdx.x * blockDim.x + threadIdx.x) >> 6);
    if (wid >= N) return;
    int lane = threadIdx.x & 63;
    int start = rowptr[wid], end = rowptr[wid + 1];
    int deg = end - start;
    const float4 ad = *(const float4*)(ad1 + (size_t)wid * 4);
    int head = lane >> 4;
    float adh = head == 0 ? ad.x : head == 1 ? ad.y : head == 2 ? ad.z : ad.w;

    float acc0 = 0.f, acc1 = 0.f;

    if (deg <= 64) {
        int idx = lane & 15;
        float ex[4];
        int sv[4];
        float den = 0.f;
        #pragma unroll
        for (int b = 0; b < 4; ++b) {
            int j = b * 16 + idx;
            float v = 0.f;
            int sc = 0;
            if (j < deg) {
                sc = col[start + j];
                v = __expf(lrelu02(as1[(size_t)sc * 4 + head] + adh));
            }
            sv[b] = sc;
            ex[b] = v;
            den += v;
        }
        den += __shfl_xor(den, 1); den += __shfl_xor(den, 2);
        den += __shfl_xor(den, 4); den += __shfl_xor(den, 8);
        float rden = 1.f / den;
        #pragma unroll
        for (int b = 0; b < 4; ++b) ex[b] *= rden;
        int srcbase = lane & 48;
        #pragma unroll
        for (int b = 0; b < 4; ++b) {
            if (b * 16 >= deg) break;
            int sq[16]; float cf[16]; unsigned hv[16];
            #pragma unroll
            for (int q = 0; q < 16; ++q) {
                sq[q] = __builtin_amdgcn_readlane(sv[b], q);   // col from exp-phase regs
                cf[q] = __shfl(ex[b], srcbase | q);            // 0 if j >= deg
            }
            #pragma unroll
            for (int q = 0; q < 16; ++q)
                hv[q] = *(const unsigned*)(h1 + (size_t)sq[q] * 128 + lane * 2);
            #pragma unroll
            for (int q = 0; q < 16; ++q) {
                acc0 = fmaf(cf[q], __uint_as_float(hv[q] << 16), acc0);
                acc1 = fmaf(cf[q], __uint_as_float(hv[q] & 0xffff0000u), acc1);
            }
        }
    } else {
        // slow path (deg > 64): recompute exp
        float den0 = 0.f, den1 = 0.f, den2 = 0.f, den3 = 0.f;
        for (int e = start + lane; e < end; e += 64) {
            int src = col[e];
            const float4 a = *(const float4*)(as1 + (size_t)src * 4);
            den0 += __expf(lrelu02(a.x + ad.x));
            den1 += __expf(lrelu02(a.y + ad.y));
            den2 += __expf(lrelu02(a.z + ad.z));
            den3 += __expf(lrelu02(a.w + ad.w));
        }
        #pragma unroll
        for (int m = 32; m >= 1; m >>= 1) {
            den0 += __shfl_xor(den0, m); den1 += __shfl_xor(den1, m);
            den2 += __shfl_xor(den2, m); den3 += __shfl_xor(den3, m);
        }
        float rden = head == 0 ? 1.f/den0 : head == 1 ? 1.f/den1 : head == 2 ? 1.f/den2 : 1.f/den3;
        for (int e = start; e < end; e += 8) {
            int sq[8]; float av[8], km[8]; unsigned hv[8];
            #pragma unroll
            for (int j = 0; j < 8; ++j) {
                int ee = e + j;
                bool ok = ee < end;
                int es = ok ? ee : e;
                sq[j] = __builtin_amdgcn_readfirstlane(col[es]);
                km[j] = ok ? 1.f : 0.f;
            }
            #pragma unroll
            for (int j = 0; j < 8; ++j)
                av[j] = as1[(size_t)sq[j] * 4 + head];
            #pragma unroll
            for (int j = 0; j < 8; ++j)
                hv[j] = *(const unsigned*)(h1 + (size_t)sq[j] * 128 + lane * 2);
            #pragma unroll
            for (int j = 0; j < 8; ++j) {
                float coef = km[j] * __expf(lrelu02(av[j] + adh)) * rden;
                acc0 = fmaf(coef, __uint_as_float(hv[j] << 16), acc0);
                acc1 = fmaf(coef, __uint_as_float(hv[j] & 0xffff0000u), acc1);
            }
        }
    }

    int c0 = lane * 2;
    float o0 = acc0 + b1[c0];
    float o1 = acc1 + b1[c0 + 1];
    o0 = o0 > 0.f ? o0 : expm1f(o0);
    o1 = o1 > 0.f ? o1 : expm1f(o1);
    unsigned ov = bf16rne(o0) | (bf16rne(o1) << 16);
    *(unsigned*)((char*)out1 + (size_t)wid * 256 + lane * 4) = ov;
}

// -------------------- GEMM2 (MFMA bf16) --------------------
__global__ __launch_bounds__(256) void k_gemm2(
    const unsigned short* __restrict__ in, const float* __restrict__ W,
    const float* __restrict__ attS, const float* __restrict__ attD,
    float* __restrict__ h2, float* __restrict__ as2, float* __restrict__ ad2, int N)
{
    __shared__ unsigned short Wt[16 * 128];
    __shared__ unsigned short xs[64 * 128];
    const int t = threadIdx.x;
    const int lane = t & 63;
    const int wv = t >> 6;
    const int ln = lane & 15;
    const int lg = lane >> 4;
    const int r0 = blockIdx.x * 64;

    #pragma unroll
    for (int i = 0; i < 2; ++i) {
        int flat = i * 256 + t;
        int n = flat & 15;
        int k0 = (flat >> 4) * 4;
        float v0 = W[(size_t)(k0 + 0) * 16 + n];
        float v1 = W[(size_t)(k0 + 1) * 16 + n];
        float v2 = W[(size_t)(k0 + 2) * 16 + n];
        float v3 = W[(size_t)(k0 + 3) * 16 + n];
        uint2 pk;
        pk.x = bf16rne(v0) | (bf16rne(v1) << 16);
        pk.y = bf16rne(v2) | (bf16rne(v3) << 16);
        int byteo = n * 256 + ((k0 * 2) ^ ((n & 7) << 4));
        *(uint2*)((char*)Wt + byteo) = pk;
    }
    #pragma unroll
    for (int it = 0; it < 4; ++it) {
        int idx = t + it * 256;
        int m = idx >> 4, o = idx & 15;
        int rr = r0 + m;
        uint4 v = make_uint4(0, 0, 0, 0);
        if (rr < N) v = *(const uint4*)((const char*)(in + (size_t)rr * 128) + o * 16);
        int byteo = m * 256 + ((o * 16) ^ ((m & 7) << 4));
        *(uint4*)((char*)xs + byteo) = v;
    }
    __syncthreads();

    f32x4 acc = (f32x4)(0.f);
    #pragma unroll
    for (int kk = 0; kk < 4; ++kk) {
        int kb = (kk * 32 + lg * 8) * 2;
        int am = wv * 16 + ln;
        short8 a = *(const short8*)((char*)xs + am * 256 + (kb ^ ((am & 7) << 4)));
        short8 b = *(const short8*)((char*)Wt + ln * 256 + (kb ^ ((ln & 7) << 4)));
        acc = __builtin_amdgcn_mfma_f32_16x16x32_bf16(a, b, acc, 0, 0, 0);
    }

    float aSv = attS[ln], aDv = attD[ln];
    #pragma unroll
    for (int r = 0; r < 4; ++r) {
        int row = r0 + wv * 16 + lg * 4 + r;
        float s = acc[r] * aSv;
        float d = acc[r] * aDv;
        s += __shfl_xor(s, 1); s += __shfl_xor(s, 2); s += __shfl_xor(s, 4); s += __shfl_xor(s, 8);
        d += __shfl_xor(d, 1); d += __shfl_xor(d, 2); d += __shfl_xor(d, 4); d += __shfl_xor(d, 8);
        if (row < N) {
            h2[(size_t)row * 16 + ln] = acc[r];
            if (ln == 0) { as2[row] = s; ad2[row] = d; }
        }
    }
}

// ---------- layer-2 fused softmax+aggregate ----------
__global__ __launch_bounds__(256) void k_agg2(
    const float* __restrict__ h2, const float* __restrict__ as2,
    const float* __restrict__ ad2, const int* __restrict__ rowptr,
    const int* __restrict__ col, const float* __restrict__ b2,
    float* __restrict__ out, int N)
{
    int wid = (int)(((unsigned)blockIdx.x * blockDim.x + threadIdx.x) >> 6);
    if (wid >= N) return;
    int lane = threadIdx.x & 63;
    int start = rowptr[wid], end = rowptr[wid + 1];
    int deg = end - start;
    float adv = ad2[wid];
    int sub = lane >> 4, c = lane & 15;
    float acc = 0.f;

    if (deg <= 64) {
        float ex0 = 0.f;
        if (lane < deg) ex0 = __expf(lrelu02(as2[col[start + lane]] + adv));
        float den = ex0;
        #pragma unroll
        for (int m = 32; m >= 1; m >>= 1) den += __shfl_xor(den, m);
        ex0 *= 1.f / den;
        #pragma unroll
        for (int g = 0; g < 4; ++g) {
            if (g * 16 >= deg) break;
            int s[4]; float cf[4], hv[4];
            #pragma unroll
            for (int jj = 0; jj < 4; ++jj) {
                int j = g * 16 + jj * 4 + sub;
                s[jj]  = col[start + (j < deg ? j : 0)];
                cf[jj] = __shfl(ex0, j);
            }
            #pragma unroll
            for (int jj = 0; jj < 4; ++jj)
                hv[jj] = h2[(size_t)s[jj] * 16 + c];
            #pragma unroll
            for (int jj = 0; jj < 4; ++jj)
                acc = fmaf(cf[jj], hv[jj], acc);
        }
    } else {
        float den = 0.f;
        for (int e = start + lane; e < end; e += 64)
            den += __expf(lrelu02(as2[col[e]] + adv));
        #pragma unroll
        for (int m = 32; m >= 1; m >>= 1) den += __shfl_xor(den, m);
        float rden = 1.f / den;
        for (int e0 = start + sub; e0 < end; e0 += 16) {
            int s[4]; float av[4], km[4], hv[4];
            #pragma unroll
            for (int jj = 0; jj < 4; ++jj) {
                int ee = e0 + jj * 4;
                bool ok = ee < end;
                int es = ok ? ee : e0;
                s[jj]  = col[es];
                km[jj] = ok ? 1.f : 0.f;
            }
            #pragma unroll
            for (int jj = 0; jj < 4; ++jj)
                av[jj] = as2[s[jj]];
            #pragma unroll
            for (int jj = 0; jj < 4; ++jj)
                hv[jj] = h2[(size_t)s[jj] * 16 + c];
            #pragma unroll
            for (int jj = 0; jj < 4; ++jj) {
                float coef = km[jj] * __expf(lrelu02(av[jj] + adv)) * rden;
                acc = fmaf(coef, hv[jj], acc);
            }
        }
    }

    acc += __shfl_xor(acc, 16);
    acc += __shfl_xor(acc, 32);
    if (lane < 16) out[(size_t)wid * 16 + lane] = acc + b2[lane];
}

extern "C" void kernel_launch(void* const* d_in, const int* in_sizes, int n_in,
                              void* d_out, int out_size, void* d_ws, size_t ws_size,
                              hipStream_t stream)
{
    const float* x   = (const float*)d_in[0];
    const int*   ei  = (const int*)d_in[1];
    const float* W1  = (const float*)d_in[2];
    const float* aS1 = (const float*)d_in[3];
    const float* aD1 = (const float*)d_in[4];
    const float* b1  = (const float*)d_in[5];
    const float* W2  = (const float*)d_in[6];
    const float* aS2 = (const float*)d_in[7];
    const float* aD2 = (const float*)d_in[8];
    const float* b2  = (const float*)d_in[9];
    float* out = (float*)d_out;

    int N = in_sizes[0] / 128;
    int E = in_sizes[1] / 2;
    int ET = E + N;
    int G1 = (N + 63) / 64;

    char* w = (char*)d_ws;
    auto alloc = [&](size_t bytes) -> void* {
        void* p = (void*)w;
        w += (bytes + 255) & ~(size_t)255;
        return p;
    };
    unsigned short* h1   = (unsigned short*)alloc((size_t)N * 128 * 2);
    unsigned short* out1 = (unsigned short*)alloc((size_t)N * 128 * 2);
    float* as1   = (float*)alloc((size_t)N * 4 * 4);
    float* ad1   = (float*)alloc((size_t)N * 4 * 4);
    float* h2    = (float*)alloc((size_t)N * 16 * 4);
    float* as2v  = (float*)alloc((size_t)N * 4);
    float* ad2v  = (float*)alloc((size_t)N * 4);
    int* deg     = (int*)alloc((size_t)N * 4);
    int* rowptr  = (int*)alloc((size_t)(N + 1) * 4);
    int* rank    = (int*)alloc((size_t)ET * 4);
    int* col     = (int*)alloc((size_t)ET * 4);
    int* bsum    = (int*)alloc(64 * 4);

    const int tb = 256;

    k_gemm1<<<G1, tb, 0, stream>>>(x, W1, aS1, aD1, h1, as1, ad1, N);

    {
        int devBlk = 0;
        hipOccupancyMaxActiveBlocksPerMultiprocessor(&devBlk, k_csr, tb, 0);
        if (devBlk < 1) devBlk = 1;
        long long grid = (long long)devBlk * 256;   // 256 CUs on MI355X
        if (grid > 2048) grid = 2048;
        int gridi = (int)grid;
        void* args[] = {(void*)&ei, (void*)&deg, (void*)&rank, (void*)&rowptr,
                        (void*)&bsum, (void*)&col, (void*)&E, (void*)&N};
        hipLaunchCooperativeKernel((const void*)k_csr, dim3(gridi), dim3(tb),
                                   args, 0, stream);
    }

    k_agg1 <<<(N + 3) / 4, tb, 0, stream>>>(h1, as1, ad1, rowptr, col, b1, out1, N);
    k_gemm2<<<G1, tb, 0, stream>>>(out1, W2, aS2, aD2, h2, as2v, ad2v, N);
    k_agg2 <<<(N + 3) / 4, tb, 0, stream>>>(h2, as2v, ad2v, rowptr, col, b2, out, N);
}

// Round 13
// 149.428 us; speedup vs baseline: 5.4450x; 5.4450x over previous
//
#include <hip/hip_runtime.h>

typedef __attribute__((ext_vector_type(8))) short short8;
typedef __attribute__((ext_vector_type(4))) float f32x4;
typedef __attribute__((ext_vector_type(2))) float f32x2;

__device__ __forceinline__ float lrelu02(float a) { return a > 0.0f ? a : 0.2f * a; }

__device__ __forceinline__ unsigned bf16rne(float f) {
    unsigned u = __float_as_uint(f);
    return (u + 0x7fffu + ((u >> 16) & 1u)) >> 16;
}

// ---------- CSR rank pass: standalone, 0 LDS -> full latency hiding ----------
__global__ __launch_bounds__(256) void k_rank(
    const int* __restrict__ ei, int* __restrict__ deg, int* __restrict__ rank,
    int E, int N)
{
    int tid = blockIdx.x * blockDim.x + threadIdx.x;
    int nthr = gridDim.x * blockDim.x;
    int E4 = E & ~3;
    for (int b = tid * 4; b < E4; b += nthr * 4) {
        int4 d = *(const int4*)(ei + E + b);
        int4 r;
        r.x = atomicAdd(&deg[d.x], 1);
        r.y = atomicAdd(&deg[d.y], 1);
        r.z = atomicAdd(&deg[d.z], 1);
        r.w = atomicAdd(&deg[d.w], 1);
        *(int4*)(rank + b) = r;
    }
    for (int e = E4 + tid; e < E; e += nthr)
        rank[e] = atomicAdd(&deg[ei[E + e]], 1);
    for (int i = tid; i < N; i += nthr)
        rank[E + i] = atomicAdd(&deg[i], 1);            // self loops
}

// -------------------- GEMM1 (MFMA bf16) + deg-zero prelude --------------------
__global__ __launch_bounds__(256) void k_gemm1(
    const float* __restrict__ x, const float* __restrict__ W,
    const float* __restrict__ attS, const float* __restrict__ attD,
    unsigned short* __restrict__ h1, float* __restrict__ as1, float* __restrict__ ad1,
    int4* __restrict__ degz, int n4, int N)
{
    __shared__ unsigned short Wt[128 * 128];
    __shared__ unsigned short xs[64 * 128];

    const int t = threadIdx.x;
    const int lane = t & 63;
    const int wv = t >> 6;
    const int ln = lane & 15;
    const int lg = lane >> 4;
    const int r0 = blockIdx.x * 64;

    // zero deg (replaces a standalone kernel; kernel boundary orders it before k_rank)
    for (int i = blockIdx.x * 256 + t; i < n4; i += gridDim.x * 256)
        degz[i] = make_int4(0, 0, 0, 0);

    #pragma unroll
    for (int i = 0; i < 16; ++i) {
        int flat = i * 256 + t;
        int n = flat & 127;
        int k0 = (flat >> 7) * 4;
        float v0 = W[(size_t)(k0 + 0) * 128 + n];
        float v1 = W[(size_t)(k0 + 1) * 128 + n];
        float v2 = W[(size_t)(k0 + 2) * 128 + n];
        float v3 = W[(size_t)(k0 + 3) * 128 + n];
        uint2 pk;
        pk.x = bf16rne(v0) | (bf16rne(v1) << 16);
        pk.y = bf16rne(v2) | (bf16rne(v3) << 16);
        int byteo = n * 256 + ((k0 * 2) ^ ((n & 7) << 4));
        *(uint2*)((char*)Wt + byteo) = pk;
    }
    {
        int mbase = t >> 5, k0 = (t & 31) * 4;
        #pragma unroll
        for (int it = 0; it < 8; ++it) {
            int m = mbase + it * 8;
            int rr = r0 + m;
            float4 v = make_float4(0.f, 0.f, 0.f, 0.f);
            if (rr < N) v = *(const float4*)&x[(size_t)rr * 128 + k0];
            unsigned lo = bf16rne(v.x) | (bf16rne(v.y) << 16);
            unsigned hi = bf16rne(v.z) | (bf16rne(v.w) << 16);
            int byteo = m * 256 + ((k0 * 2) ^ ((m & 7) << 4));
            *(uint2*)((char*)xs + byteo) = make_uint2(lo, hi);
        }
    }
    __syncthreads();

    f32x4 acc[8];
    #pragma unroll
    for (int i = 0; i < 8; ++i) acc[i] = (f32x4)(0.f);

    #pragma unroll
    for (int kk = 0; kk < 4; ++kk) {
        int kb = (kk * 32 + lg * 8) * 2;
        int am = wv * 16 + ln;
        short8 a = *(const short8*)((char*)xs + am * 256 + (kb ^ ((am & 7) << 4)));
        #pragma unroll
        for (int tile = 0; tile < 8; ++tile) {
            int n = tile * 16 + ln;
            short8 b = *(const short8*)((char*)Wt + n * 256 + (kb ^ ((n & 7) << 4)));
            acc[tile] = __builtin_amdgcn_mfma_f32_16x16x32_bf16(a, b, acc[tile], 0, 0, 0);
        }
    }

    float aSt[8], aDt[8];
    #pragma unroll
    for (int tile = 0; tile < 8; ++tile) {
        aSt[tile] = attS[tile * 16 + ln];
        aDt[tile] = attD[tile * 16 + ln];
    }
    #pragma unroll
    for (int r = 0; r < 4; ++r) {
        int row = r0 + wv * 16 + lg * 4 + r;
        #pragma unroll
        for (int h = 0; h < 4; ++h) {
            float s = acc[2*h][r] * aSt[2*h] + acc[2*h+1][r] * aSt[2*h+1];
            float d = acc[2*h][r] * aDt[2*h] + acc[2*h+1][r] * aDt[2*h+1];
            s += __shfl_xor(s, 1); s += __shfl_xor(s, 2); s += __shfl_xor(s, 4); s += __shfl_xor(s, 8);
            d += __shfl_xor(d, 1); d += __shfl_xor(d, 2); d += __shfl_xor(d, 4); d += __shfl_xor(d, 8);
            if (ln == h * 4 + r && row < N) {
                as1[row * 4 + h] = s;
                ad1[row * 4 + h] = d;
            }
        }
    }

    __syncthreads();
    #pragma unroll
    for (int tile = 0; tile < 8; ++tile) {
        #pragma unroll
        for (int r = 0; r < 4; ++r) {
            int m = wv * 16 + lg * 4 + r;
            int byteo = m * 256 + (((tile * 16 + ln) * 2) ^ ((m & 7) << 4));
            *(unsigned short*)((char*)xs + byteo) = (unsigned short)bf16rne(acc[tile][r]);
        }
    }
    __syncthreads();
    #pragma unroll
    for (int it = 0; it < 4; ++it) {
        int idx = t + it * 256;
        int m = idx >> 4, o = idx & 15;
        int byteo = m * 256 + ((o * 16) ^ ((m & 7) << 4));
        if (r0 + m < N)
            *(uint4*)((char*)(h1 + (size_t)(r0 + m) * 128) + o * 16) =
                *(const uint4*)((const char*)xs + byteo);
    }
}

// -------------------- hierarchical scan --------------------
__global__ __launch_bounds__(256) void k_scan_local(
    const int* __restrict__ deg, int* __restrict__ rowptr, int* __restrict__ bsum, int N)
{
    const int t = threadIdx.x;
    const int base = blockIdx.x * 2048 + t * 8;
    int v[8];
    int s = 0;
    #pragma unroll
    for (int j = 0; j < 8; ++j) {
        int idx = base + j;
        v[j] = (idx < N) ? deg[idx] : 0;
        s += v[j];
    }
    __shared__ int ts[256];
    ts[t] = s;
    __syncthreads();
    #pragma unroll
    for (int off = 1; off < 256; off <<= 1) {
        int u = (t >= off) ? ts[t - off] : 0;
        __syncthreads();
        ts[t] += u;
        __syncthreads();
    }
    int ex = (t == 0) ? 0 : ts[t - 1];
    #pragma unroll
    for (int j = 0; j < 8; ++j) {
        int idx = base + j;
        if (idx < N) rowptr[idx] = ex;
        ex += v[j];
    }
    if (t == 255) bsum[blockIdx.x] = ts[255];
}

__global__ __launch_bounds__(256) void k_scan_add(
    int* __restrict__ rowptr, const int* __restrict__ bsum, int N, int ET)
{
    const int t = threadIdx.x;
    __shared__ int soff;
    if (t < 64) {
        int v = (t < (int)blockIdx.x) ? bsum[t] : 0;    // nblk <= 64
        #pragma unroll
        for (int m = 32; m >= 1; m >>= 1) v += __shfl_xor(v, m);
        if (t == 0) soff = v;
    }
    __syncthreads();
    int off = soff;
    const int base = blockIdx.x * 2048 + t * 8;
    #pragma unroll
    for (int j = 0; j < 8; ++j) {
        int idx = base + j;
        if (idx < N) rowptr[idx] += off;
    }
    if (blockIdx.x == 0 && t == 0) rowptr[N] = ET;
}

// -------------------- CSR fill: atomic-free --------------------
__global__ __launch_bounds__(256) void k_fill2(const int* __restrict__ ei,
                                               const int* __restrict__ rank,
                                               const int* __restrict__ rowptr,
                                               int* __restrict__ col, int E, int N) {
    int tid = blockIdx.x * blockDim.x + threadIdx.x;
    int nthr = gridDim.x * blockDim.x;
    int E4 = E & ~3;
    for (int b = tid * 4; b < E4; b += nthr * 4) {
        int4 d = *(const int4*)(ei + E + b);
        int4 s = *(const int4*)(ei + b);
        int4 r = *(const int4*)(rank + b);
        col[rowptr[d.x] + r.x] = s.x;
        col[rowptr[d.y] + r.y] = s.y;
        col[rowptr[d.z] + r.z] = s.z;
        col[rowptr[d.w] + r.w] = s.w;
    }
    for (int e = E4 + tid; e < E; e += nthr)
        col[rowptr[ei[E + e]] + rank[e]] = ei[e];
    for (int i = tid; i < N; i += nthr)
        col[rowptr[i] + rank[E + i]] = i;
}

// ---------- layer-1 fused softmax+aggregate ----------
// fast path (deg<=64): 1 exp/lane; full-16 batches + 4-granular tail; pk-fma accumulate.
__global__ __launch_bounds__(256) void k_agg1(
    const unsigned short* __restrict__ h1, const float* __restrict__ as1,
    const float* __restrict__ ad1, const int* __restrict__ rowptr,
    const int* __restrict__ col, const float* __restrict__ b1,
    unsigned short* __restrict__ out1, int N)
{
    int wid = (int)(((unsigned)blockIdx.x * blockDim.x + threadIdx.x) >> 6);
    if (wid >= N) return;
    int lane = threadIdx.x & 63;
    int start = rowptr[wid], end = rowptr[wid + 1];
    int deg = end - start;
    const float4 ad = *(const float4*)(ad1 + (size_t)wid * 4);
    int head = lane >> 4;
    float adh = head == 0 ? ad.x : head == 1 ? ad.y : head == 2 ? ad.z : ad.w;

    f32x2 acc2 = (f32x2)(0.f);

    if (deg <= 64) {
        int idx = lane & 15;
        float ex[4];
        int sv[4];
        float den = 0.f;
        #pragma unroll
        for (int b = 0; b < 4; ++b) {
            int j = b * 16 + idx;
            float v = 0.f;
            int sc = 0;
            if (j < deg) {
                sc = col[start + j];
                v = __expf(lrelu02(as1[(size_t)sc * 4 + head] + adh));
            }
            sv[b] = sc;
            ex[b] = v;
            den += v;
        }
        den += __shfl_xor(den, 1); den += __shfl_xor(den, 2);
        den += __shfl_xor(den, 4); den += __shfl_xor(den, 8);
        float rden = 1.f / den;
        #pragma unroll
        for (int b = 0; b < 4; ++b) ex[b] *= rden;
        int srcbase = lane & 48;

        #pragma unroll
        for (int b = 0; b < 4; ++b) {
            int rem = deg - b * 16;
            if (rem <= 0) break;
            if (rem >= 16) {
                // full batch: 16 gathers in flight
                int sq[16]; float cf[16]; unsigned hv[16];
                #pragma unroll
                for (int q = 0; q < 16; ++q) {
                    sq[q] = __builtin_amdgcn_readlane(sv[b], q);
                    cf[q] = __shfl(ex[b], srcbase | q);
                }
                #pragma unroll
                for (int q = 0; q < 16; ++q)
                    hv[q] = *(const unsigned*)(h1 + (size_t)sq[q] * 128 + lane * 2);
                #pragma unroll
                for (int q = 0; q < 16; ++q) {
                    f32x2 h2v;
                    h2v.x = __uint_as_float(hv[q] << 16);
                    h2v.y = __uint_as_float(hv[q] & 0xffff0000u);
                    acc2 += (f32x2)(cf[q]) * h2v;
                }
            } else {
                // tail: 4-edge chunks behind wave-uniform guards (zeros pad within chunk)
                #pragma unroll
                for (int c4 = 0; c4 < 4; ++c4) {
                    if (c4 * 4 >= rem) break;
                    int sq[4]; float cf[4]; unsigned hv[4];
                    #pragma unroll
                    for (int jj = 0; jj < 4; ++jj) {
                        int q = c4 * 4 + jj;
                        sq[jj] = __builtin_amdgcn_readlane(sv[b], q);
                        cf[jj] = __shfl(ex[b], srcbase | q);    // 0 beyond deg
                    }
                    #pragma unroll
                    for (int jj = 0; jj < 4; ++jj)
                        hv[jj] = *(const unsigned*)(h1 + (size_t)sq[jj] * 128 + lane * 2);
                    #pragma unroll
                    for (int jj = 0; jj < 4; ++jj) {
                        f32x2 h2v;
                        h2v.x = __uint_as_float(hv[jj] << 16);
                        h2v.y = __uint_as_float(hv[jj] & 0xffff0000u);
                        acc2 += (f32x2)(cf[jj]) * h2v;
                    }
                }
            }
        }
    } else {
        // slow path (deg > 64): recompute exp
        float den0 = 0.f, den1 = 0.f, den2 = 0.f, den3 = 0.f;
        for (int e = start + lane; e < end; e += 64) {
            int src = col[e];
            const float4 a = *(const float4*)(as1 + (size_t)src * 4);
            den0 += __expf(lrelu02(a.x + ad.x));
            den1 += __expf(lrelu02(a.y + ad.y));
            den2 += __expf(lrelu02(a.z + ad.z));
            den3 += __expf(lrelu02(a.w + ad.w));
        }
        #pragma unroll
        for (int m = 32; m >= 1; m >>= 1) {
            den0 += __shfl_xor(den0, m); den1 += __shfl_xor(den1, m);
            den2 += __shfl_xor(den2, m); den3 += __shfl_xor(den3, m);
        }
        float rden = head == 0 ? 1.f/den0 : head == 1 ? 1.f/den1 : head == 2 ? 1.f/den2 : 1.f/den3;
        for (int e = start; e < end; e += 8) {
            int sq[8]; float av[8], km[8]; unsigned hv[8];
            #pragma unroll
            for (int j = 0; j < 8; ++j) {
                int ee = e + j;
                bool ok = ee < end;
                int es = ok ? ee : e;
                sq[j] = __builtin_amdgcn_readfirstlane(col[es]);
                km[j] = ok ? 1.f : 0.f;
            }
            #pragma unroll
            for (int j = 0; j < 8; ++j)
                av[j] = as1[(size_t)sq[j] * 4 + head];
            #pragma unroll
            for (int j = 0; j < 8; ++j)
                hv[j] = *(const unsigned*)(h1 + (size_t)sq[j] * 128 + lane * 2);
            #pragma unroll
            for (int j = 0; j < 8; ++j) {
                float coef = km[j] * __expf(lrelu02(av[j] + adh)) * rden;
                f32x2 h2v;
                h2v.x = __uint_as_float(hv[j] << 16);
                h2v.y = __uint_as_float(hv[j] & 0xffff0000u);
                acc2 += (f32x2)(coef) * h2v;
            }
        }
    }

    int c0 = lane * 2;
    float o0 = acc2.x + b1[c0];
    float o1 = acc2.y + b1[c0 + 1];
    o0 = o0 > 0.f ? o0 : expm1f(o0);
    o1 = o1 > 0.f ? o1 : expm1f(o1);
    unsigned ov = bf16rne(o0) | (bf16rne(o1) << 16);
    *(unsigned*)((char*)out1 + (size_t)wid * 256 + lane * 4) = ov;
}

// -------------------- GEMM2 (MFMA bf16) --------------------
__global__ __launch_bounds__(256) void k_gemm2(
    const unsigned short* __restrict__ in, const float* __restrict__ W,
    const float* __restrict__ attS, const float* __restrict__ attD,
    float* __restrict__ h2, float* __restrict__ as2, float* __restrict__ ad2, int N)
{
    __shared__ unsigned short Wt[16 * 128];
    __shared__ unsigned short xs[64 * 128];
    const int t = threadIdx.x;
    const int lane = t & 63;
    const int wv = t >> 6;
    const int ln = lane & 15;
    const int lg = lane >> 4;
    const int r0 = blockIdx.x * 64;

    #pragma unroll
    for (int i = 0; i < 2; ++i) {
        int flat = i * 256 + t;
        int n = flat & 15;
        int k0 = (flat >> 4) * 4;
        float v0 = W[(size_t)(k0 + 0) * 16 + n];
        float v1 = W[(size_t)(k0 + 1) * 16 + n];
        float v2 = W[(size_t)(k0 + 2) * 16 + n];
        float v3 = W[(size_t)(k0 + 3) * 16 + n];
        uint2 pk;
        pk.x = bf16rne(v0) | (bf16rne(v1) << 16);
        pk.y = bf16rne(v2) | (bf16rne(v3) << 16);
        int byteo = n * 256 + ((k0 * 2) ^ ((n & 7) << 4));
        *(uint2*)((char*)Wt + byteo) = pk;
    }
    #pragma unroll
    for (int it = 0; it < 4; ++it) {
        int idx = t + it * 256;
        int m = idx >> 4, o = idx & 15;
        int rr = r0 + m;
        uint4 v = make_uint4(0, 0, 0, 0);
        if (rr < N) v = *(const uint4*)((const char*)(in + (size_t)rr * 128) + o * 16);
        int byteo = m * 256 + ((o * 16) ^ ((m & 7) << 4));
        *(uint4*)((char*)xs + byteo) = v;
    }
    __syncthreads();

    f32x4 acc = (f32x4)(0.f);
    #pragma unroll
    for (int kk = 0; kk < 4; ++kk) {
        int kb = (kk * 32 + lg * 8) * 2;
        int am = wv * 16 + ln;
        short8 a = *(const short8*)((char*)xs + am * 256 + (kb ^ ((am & 7) << 4)));
        short8 b = *(const short8*)((char*)Wt + ln * 256 + (kb ^ ((ln & 7) << 4)));
        acc = __builtin_amdgcn_mfma_f32_16x16x32_bf16(a, b, acc, 0, 0, 0);
    }

    float aSv = attS[ln], aDv = attD[ln];
    #pragma unroll
    for (int r = 0; r < 4; ++r) {
        int row = r0 + wv * 16 + lg * 4 + r;
        float s = acc[r] * aSv;
        float d = acc[r] * aDv;
        s += __shfl_xor(s, 1); s += __shfl_xor(s, 2); s += __shfl_xor(s, 4); s += __shfl_xor(s, 8);
        d += __shfl_xor(d, 1); d += __shfl_xor(d, 2); d += __shfl_xor(d, 4); d += __shfl_xor(d, 8);
        if (row < N) {
            h2[(size_t)row * 16 + ln] = acc[r];
            if (ln == 0) { as2[row] = s; ad2[row] = d; }
        }
    }
}

// ---------- layer-2 fused softmax+aggregate ----------
__global__ __launch_bounds__(256) void k_agg2(
    const float* __restrict__ h2, const float* __restrict__ as2,
    const float* __restrict__ ad2, const int* __restrict__ rowptr,
    const int* __restrict__ col, const float* __restrict__ b2,
    float* __restrict__ out, int N)
{
    int wid = (int)(((unsigned)blockIdx.x * blockDim.x + threadIdx.x) >> 6);
    if (wid >= N) return;
    int lane = threadIdx.x & 63;
    int start = rowptr[wid], end = rowptr[wid + 1];
    int deg = end - start;
    float adv = ad2[wid];
    int sub = lane >> 4, c = lane & 15;
    float acc = 0.f;

    if (deg <= 64) {
        float ex0 = 0.f;
        if (lane < deg) ex0 = __expf(lrelu02(as2[col[start + lane]] + adv));
        float den = ex0;
        #pragma unroll
        for (int m = 32; m >= 1; m >>= 1) den += __shfl_xor(den, m);
        ex0 *= 1.f / den;
        #pragma unroll
        for (int g = 0; g < 4; ++g) {
            if (g * 16 >= deg) break;
            int s[4]; float cf[4], hv[4];
            #pragma unroll
            for (int jj = 0; jj < 4; ++jj) {
                int j = g * 16 + jj * 4 + sub;
                s[jj]  = col[start + (j < deg ? j : 0)];
                cf[jj] = __shfl(ex0, j);                // 0 if j >= deg
            }
            #pragma unroll
            for (int jj = 0; jj < 4; ++jj)
                hv[jj] = h2[(size_t)s[jj] * 16 + c];
            #pragma unroll
            for (int jj = 0; jj < 4; ++jj)
                acc = fmaf(cf[jj], hv[jj], acc);
        }
    } else {
        float den = 0.f;
        for (int e = start + lane; e < end; e += 64)
            den += __expf(lrelu02(as2[col[e]] + adv));
        #pragma unroll
        for (int m = 32; m >= 1; m >>= 1) den += __shfl_xor(den, m);
        float rden = 1.f / den;
        for (int e0 = start + sub; e0 < end; e0 += 16) {
            int s[4]; float av[4], km[4], hv[4];
            #pragma unroll
            for (int jj = 0; jj < 4; ++jj) {
                int ee = e0 + jj * 4;
                bool ok = ee < end;
                int es = ok ? ee : e0;
                s[jj]  = col[es];
                km[jj] = ok ? 1.f : 0.f;
            }
            #pragma unroll
            for (int jj = 0; jj < 4; ++jj)
                av[jj] = as2[s[jj]];
            #pragma unroll
            for (int jj = 0; jj < 4; ++jj)
                hv[jj] = h2[(size_t)s[jj] * 16 + c];
            #pragma unroll
            for (int jj = 0; jj < 4; ++jj) {
                float coef = km[jj] * __expf(lrelu02(av[jj] + adv)) * rden;
                acc = fmaf(coef, hv[jj], acc);
            }
        }
    }

    acc += __shfl_xor(acc, 16);
    acc += __shfl_xor(acc, 32);
    if (lane < 16) out[(size_t)wid * 16 + lane] = acc + b2[lane];
}

extern "C" void kernel_launch(void* const* d_in, const int* in_sizes, int n_in,
                              void* d_out, int out_size, void* d_ws, size_t ws_size,
                              hipStream_t stream)
{
    const float* x   = (const float*)d_in[0];
    const int*   ei  = (const int*)d_in[1];
    const float* W1  = (const float*)d_in[2];
    const float* aS1 = (const float*)d_in[3];
    const float* aD1 = (const float*)d_in[4];
    const float* b1  = (const float*)d_in[5];
    const float* W2  = (const float*)d_in[6];
    const float* aS2 = (const float*)d_in[7];
    const float* aD2 = (const float*)d_in[8];
    const float* b2  = (const float*)d_in[9];
    float* out = (float*)d_out;

    int N = in_sizes[0] / 128;
    int E = in_sizes[1] / 2;
    int ET = E + N;
    int nblk = (N + 2047) / 2048;
    int G1 = (N + 63) / 64;

    char* w = (char*)d_ws;
    auto alloc = [&](size_t bytes) -> void* {
        void* p = (void*)w;
        w += (bytes + 255) & ~(size_t)255;
        return p;
    };
    unsigned short* h1   = (unsigned short*)alloc((size_t)N * 128 * 2);
    unsigned short* out1 = (unsigned short*)alloc((size_t)N * 128 * 2);
    float* as1   = (float*)alloc((size_t)N * 4 * 4);
    float* ad1   = (float*)alloc((size_t)N * 4 * 4);
    float* h2    = (float*)alloc((size_t)N * 16 * 4);
    float* as2v  = (float*)alloc((size_t)N * 4);
    float* ad2v  = (float*)alloc((size_t)N * 4);
    int* deg     = (int*)alloc((size_t)(N + 4) * 4);
    int* rowptr  = (int*)alloc((size_t)(N + 1) * 4);
    int* rank    = (int*)alloc((size_t)ET * 4);
    int* col     = (int*)alloc((size_t)ET * 4);
    int* bsum    = (int*)alloc(64 * 4);

    const int tb = 256;
    int n4 = (N + 3) / 4;

    k_gemm1 <<<G1, tb, 0, stream>>>(x, W1, aS1, aD1, h1, as1, ad1, (int4*)deg, n4, N);
    k_rank  <<<2048, tb, 0, stream>>>(ei, deg, rank, E, N);
    k_scan_local<<<nblk, tb, 0, stream>>>(deg, rowptr, bsum, N);
    k_scan_add  <<<nblk, tb, 0, stream>>>(rowptr, bsum, N, ET);
    k_fill2     <<<1024, tb, 0, stream>>>(ei, rank, rowptr, col, E, N);

    k_agg1 <<<(N + 3) / 4, tb, 0, stream>>>(h1, as1, ad1, rowptr, col, b1, out1, N);
    k_gemm2<<<G1, tb, 0, stream>>>(out1, W2, aS2, aD2, h2, as2v, ad2v, N);
    k_agg2 <<<(N + 3) / 4, tb, 0, stream>>>(h2, as2v, ad2v, rowptr, col, b2, out, N);
}